// Round 1
// baseline (23679.991 us; speedup 1.0000x reference)
//
#include <hip/hip_runtime.h>
#include <cstdint>
#include <cstddef>

// 4-layer projected LSTM. B=64 T=256 D=512 H=1024 P=256. fp32 in/out.
// Split-bf16 (hi+lo) MFMA operands, 3 MFMAs per product (absmax 6e-5).
//
// Round-7 (from 23.4 ms, all pipes <4% -> latency/sync bound, ~9us/phase
// unexplained by compute):
//  1. Two-level release barrier: arrivals striped over 32 counters (as
//     before), but only WG0 scans them -- with 32 PARALLEL LANES (one load
//     per lane per scan, a single pipelined memory op) instead of 32
//     program-ordered atomic loads per polling WG. WG0 then writes a single
//     release word; all other WGs poll ONE line with ONE load/iter.
//     Theory: sequenced agent-scope atomic loads in the old scan were not
//     being pipelined by the compiler => ~32 serialized L3 latencies per
//     scan => ~the whole 9us/phase. New barrier is ~2-3 L3 round trips.
//  2. unroll 4 -> 8 on the three 16-iter coherent-load GEMM loops (l>0
//     input, recurrent, phase-2 hP): halves exposed L3 latency batches.
//  Numerics unchanged from round-6.
// Workspace: [cnt 4K][hP 256K][Y0 16M][Y1 16M] ~= 33.8 MB (fallback: Y1=Y0).

#define B_ 64
#define T_ 256
#define D_ 512
#define H_ 1024
#define P_ 256
#define NWG 128
#define NTHR 128
#define UPW 8
#define WSTRIDE 776    // 768 + 8 pad (16B-aligned rows)

using short8  = __attribute__((ext_vector_type(8))) short;
using f32x16  = __attribute__((ext_vector_type(16))) float;
using f32x4   = __attribute__((ext_vector_type(4))) float;

__device__ inline float bf2f(short s) {
  unsigned u = ((unsigned)(unsigned short)s) << 16;
  return __builtin_bit_cast(float, u);
}
__device__ inline unsigned short f2bf(float f) {
  unsigned u = __builtin_bit_cast(unsigned, f);
  u += 0x7fffu + ((u >> 16) & 1u);   // RTNE
  return (unsigned short)(u >> 16);
}
__device__ inline void split1(float v, short& hi, short& lo) {
  unsigned short h = f2bf(v);
  hi = (short)h;
  lo = (short)f2bf(v - bf2f((short)h));
}
__device__ inline unsigned packf(float v) {
  short h, l;
  split1(v, h, l);
  return (unsigned)(unsigned short)h | ((unsigned)(unsigned short)l << 16);
}
__device__ inline void split8(const float* p, short8& hi, short8& lo) {
  float4 a = *(const float4*)p;
  float4 b = *(const float4*)(p + 4);
  float v[8] = {a.x, a.y, a.z, a.w, b.x, b.y, b.z, b.w};
#pragma unroll
  for (int i = 0; i < 8; ++i) {
    short h, l;
    split1(v[i], h, l);
    hi[i] = h; lo[i] = l;
  }
}
// 8 packed elems via normal cached loads
__device__ inline void unpack_c8(const unsigned* p, short8& hi, short8& lo) {
  uint4 a = *(const uint4*)p;
  uint4 b = *(const uint4*)(p + 4);
  unsigned w[8] = {a.x, a.y, a.z, a.w, b.x, b.y, b.z, b.w};
#pragma unroll
  for (int i = 0; i < 8; ++i) {
    hi[i] = (short)(w[i] & 0xffff);
    lo[i] = (short)(w[i] >> 16);
  }
}
// 8 packed elems via agent-coherent (L2-bypassing) loads
__device__ inline void unpack_a8(const unsigned* p, short8& hi, short8& lo) {
#pragma unroll
  for (int i = 0; i < 4; ++i) {
    unsigned long long v = __hip_atomic_load((const unsigned long long*)p + i,
                                             __ATOMIC_RELAXED, __HIP_MEMORY_SCOPE_AGENT);
    unsigned w0 = (unsigned)v, w1 = (unsigned)(v >> 32);
    hi[2 * i]     = (short)(w0 & 0xffff);
    lo[2 * i]     = (short)(w0 >> 16);
    hi[2 * i + 1] = (short)(w1 & 0xffff);
    lo[2 * i + 1] = (short)(w1 >> 16);
  }
}
__device__ inline float sigm(float x)   { return 1.f / (1.f + __expf(-x)); }
__device__ inline float tanh_f(float x) { return 1.f - 2.f / (__expf(2.f * x) + 1.f); }

// Two-level fence-free grid barrier.
//  - Arrivals striped over 32 counters, 64B apart (4 arrivals each).
//  - WG0 wave0: 32 lanes each load ONE stripe (single pipelined memory op),
//    __all-reduce, then lane 0 stores the epoch into a release word.
//  - All other WGs: lane 0 polls the single release word (1 load / iter).
// ep must increase by exactly 1 per call, starting at 1.
#define NCNT 32
#define REL_IDX 768   // u32 index of release word (byte 3072, own line)
__device__ inline void gbar(unsigned* cnt, unsigned ep) {
  __syncthreads();   // drains vmcnt: all sc1/agent stores globally visible
  if (blockIdx.x == 0) {
    if (threadIdx.x < 64) {                // wave 0 scans in parallel
      if (threadIdx.x == 0)
        __hip_atomic_fetch_add(&cnt[0], 1u, __ATOMIC_RELAXED,
                               __HIP_MEMORY_SCOPE_AGENT);
      const unsigned tgt = ep * (NWG / NCNT);
      for (;;) {
        unsigned v = tgt;                  // lanes 32..63: trivially done
        if (threadIdx.x < NCNT)
          v = __hip_atomic_load(&cnt[threadIdx.x * 16], __ATOMIC_RELAXED,
                                __HIP_MEMORY_SCOPE_AGENT);
        if (__all(v >= tgt)) break;
        __builtin_amdgcn_s_sleep(2);
      }
      if (threadIdx.x == 0)
        __hip_atomic_store(&cnt[REL_IDX], ep, __ATOMIC_RELAXED,
                           __HIP_MEMORY_SCOPE_AGENT);
    }
  } else {
    if (threadIdx.x == 0) {
      __hip_atomic_fetch_add(&cnt[(blockIdx.x & (NCNT - 1)) * 16], 1u,
                             __ATOMIC_RELAXED, __HIP_MEMORY_SCOPE_AGENT);
      while (__hip_atomic_load(&cnt[REL_IDX], __ATOMIC_RELAXED,
                               __HIP_MEMORY_SCOPE_AGENT) < ep)
        __builtin_amdgcn_s_sleep(2);
    }
  }
  __syncthreads();
}

__global__ __launch_bounds__(NTHR) void lstm_kernel(
    const float* __restrict__ x,
    const float* __restrict__ Wih0, const float* __restrict__ Whh0,
    const float* __restrict__ bih0, const float* __restrict__ bhh0,
    const float* __restrict__ Whr0,
    const float* __restrict__ Wihs, const float* __restrict__ Whhs,
    const float* __restrict__ bihs, const float* __restrict__ bhhs,
    const float* __restrict__ Whrs,
    float* __restrict__ out,
    unsigned* __restrict__ Y0, unsigned* __restrict__ Y1,
    unsigned* __restrict__ hP, unsigned* __restrict__ cnt)
{
  __shared__ short sWh[32 * WSTRIDE];   // 49664 B
  __shared__ short sWl[32 * WSTRIDE];   // 49664 B
  __shared__ float sBias[32];
  __shared__ float sG[64 * 32];         // 8192 B
  __shared__ float sRed[64 * 4];        // 1024 B (phase-2 cross-wave reduce)

  const int tid  = threadIdx.x;
  const int wg   = blockIdx.x;
  const int lane = tid & 63;
  const int wave = tid >> 6;
  const bool pp  = (Y0 != Y1);          // ping-pong mode
  unsigned ep = 0;

  // mfma_f32_32x32x16_bf16 lane geometry:
  //   A[m][k]: m = lane&31 (+ wave*32), k = (lane>>5)*8 + j
  //   B[k][n] = W[n][k]: n = lane&31
  //   D: col = lane&31, row = (reg&3) + 8*(reg>>2) + 4*(lane>>5)
  const int m1  = wave * 32 + (lane & 31);  // batch row
  const int n1  = lane & 31;                // local gate row
  const int kh1 = (lane >> 5) * 8;

  for (int l = 0; l < 4; ++l) {
    const int K1 = (l == 0) ? D_ : P_;
    const float* Wih = (l == 0) ? Wih0 : Wihs + (size_t)(l - 1) * 4096 * 256;
    const float* Whh = (l == 0) ? Whh0 : Whhs + (size_t)(l - 1) * 4096 * 256;
    const float* bih = (l == 0) ? bih0 : bihs + (size_t)(l - 1) * 4096;
    const float* bhh = (l == 0) ? bhh0 : bhhs + (size_t)(l - 1) * 4096;
    const float* Whr = (l == 0) ? Whr0 : Whrs + (size_t)(l - 1) * 256 * 1024;
    // ping-pong: l0: x->Y0, l1: Y0->Y1, l2: Y1->Y0, l3: Y0->Y1
    const unsigned* yIn = (l & 1) ? Y0 : Y1;   // unused for l==0
    unsigned*       yOut = (l & 1) ? Y1 : Y0;

    // ---- stage weight slice (split hi/lo) + bias into LDS ----
    {
      const int cpr = (K1 + P_) >> 3;
      for (int c = tid; c < 32 * cpr; c += NTHR) {
        int r = c / cpr;
        int k = (c - r * cpr) * 8;
        int R = (r & 3) * H_ + wg * UPW + (r >> 2);   // gate*H + unit
        const float* src = (k < K1) ? (Wih + (size_t)R * K1 + k)
                                    : (Whh + (size_t)R * P_ + (k - K1));
        short8 hi, lo;
        split8(src, hi, lo);
        *(short8*)&sWh[r * WSTRIDE + k] = hi;
        *(short8*)&sWl[r * WSTRIDE + k] = lo;
      }
      if (tid < 32) {
        int r = tid;
        int R = (r & 3) * H_ + wg * UPW + (r >> 2);
        sBias[r] = bih[R] + bhh[R];
      }
      __syncthreads();
      // Per-layer L2 invalidate: kills stale lines from the buffer's use two
      // layers ago and from the previous graph-replay launch.
      __threadfence();
    }

    float cs0 = 0.f, cs1 = 0.f, cs2 = 0.f, cs3 = 0.f;

    for (int t = 0; t < T_; ++t) {
      // ================= phase 1: gates + state update =================
      // 3 independent accumulator chains (hh / hl / lh) -> MFMA pipelining.
      f32x16 ahh = {}, ahl = {}, alh = {};
      {
        const short* bwh = &sWh[n1 * WSTRIDE + kh1];
        const short* bwl = &sWl[n1 * WSTRIDE + kh1];
        if (l == 0) {
          const float* axf = x + ((size_t)m1 * T_ + t) * D_ + kh1;
#pragma unroll 4
          for (int k0 = 0; k0 < D_; k0 += 16) {
            short8 Ah, Al;
            split8(axf + k0, Ah, Al);
            short8 Bh = *(const short8*)(bwh + k0);
            short8 Bl = *(const short8*)(bwl + k0);
            ahh = __builtin_amdgcn_mfma_f32_32x32x16_bf16(Ah, Bh, ahh, 0, 0, 0);
            ahl = __builtin_amdgcn_mfma_f32_32x32x16_bf16(Ah, Bl, ahl, 0, 0, 0);
            alh = __builtin_amdgcn_mfma_f32_32x32x16_bf16(Al, Bh, alh, 0, 0, 0);
          }
        } else {
          const unsigned* ypi = yIn + ((size_t)t * B_ + m1) * P_ + kh1;
#pragma unroll 8
          for (int k0 = 0; k0 < P_; k0 += 16) {
            short8 Ah, Al;
            unpack_c8(ypi + k0, Ah, Al);
            short8 Bh = *(const short8*)(bwh + k0);
            short8 Bl = *(const short8*)(bwl + k0);
            ahh = __builtin_amdgcn_mfma_f32_32x32x16_bf16(Ah, Bh, ahh, 0, 0, 0);
            ahl = __builtin_amdgcn_mfma_f32_32x32x16_bf16(Ah, Bl, ahl, 0, 0, 0);
            alh = __builtin_amdgcn_mfma_f32_32x32x16_bf16(Al, Bh, alh, 0, 0, 0);
          }
        }
        if (t > 0) {   // recurrent y[t-1] (own output, 1 epoch old)
          const unsigned* ypr = yOut + ((size_t)(t - 1) * B_ + m1) * P_ + kh1;
          const short* bhh_h = bwh + K1;
          const short* bhh_l = bwl + K1;
#pragma unroll 8
          for (int k0 = 0; k0 < P_; k0 += 16) {
            short8 Ah, Al;
            if (pp) unpack_c8(ypr + k0, Ah, Al);   // cached: sc1-written, read-once
            else    unpack_a8(ypr + k0, Ah, Al);   // in-place fallback: coherent
            short8 Bh = *(const short8*)(bhh_h + k0);
            short8 Bl = *(const short8*)(bhh_l + k0);
            ahh = __builtin_amdgcn_mfma_f32_32x32x16_bf16(Ah, Bh, ahh, 0, 0, 0);
            ahl = __builtin_amdgcn_mfma_f32_32x32x16_bf16(Ah, Bl, ahl, 0, 0, 0);
            alh = __builtin_amdgcn_mfma_f32_32x32x16_bf16(Al, Bh, alh, 0, 0, 0);
          }
        }
      }
#pragma unroll
      for (int r = 0; r < 16; ++r) {
        int mrow = (r & 3) + 8 * (r >> 2) + 4 * (lane >> 5) + wave * 32;
        sG[mrow * 32 + n1] = ahh[r] + ahl[r] + alh[r];
      }
      __syncthreads();
      {
        const int b  = tid >> 1;
        const int u4 = (tid & 1) * 4;
        const float* gp = &sG[b * 32];
        float cr[4] = {cs0, cs1, cs2, cs3};
        unsigned pw[4];
#pragma unroll
        for (int j = 0; j < 4; ++j) {
          int u = u4 + j;
          float ii = sigm(gp[u * 4 + 0] + sBias[u * 4 + 0]);
          float ff = sigm(gp[u * 4 + 1] + sBias[u * 4 + 1]);
          float gg = tanh_f(gp[u * 4 + 2] + sBias[u * 4 + 2]);
          float oo = sigm(gp[u * 4 + 3] + sBias[u * 4 + 3]);
          float cv = ff * cr[j] + ii * gg;
          cr[j] = cv;
          pw[j] = packf(oo * tanh_f(cv));
        }
        cs0 = cr[0]; cs1 = cr[1]; cs2 = cr[2]; cs3 = cr[3];
        size_t ho = (size_t)b * H_ + wg * UPW + u4;
        unsigned long long q0 = (unsigned long long)pw[0] | ((unsigned long long)pw[1] << 32);
        unsigned long long q1 = (unsigned long long)pw[2] | ((unsigned long long)pw[3] << 32);
        __hip_atomic_store((unsigned long long*)&hP[ho], q0,
                           __ATOMIC_RELAXED, __HIP_MEMORY_SCOPE_AGENT);
        __hip_atomic_store((unsigned long long*)&hP[ho + 2], q1,
                           __ATOMIC_RELAXED, __HIP_MEMORY_SCOPE_AGENT);
      }
      ep++; gbar(cnt, ep);

      // ================= phase 2: projection y_t = h @ Whr^T ===========
      // WGs 0..63, BOTH waves: wave w handles K in [w*512, w*512+512).
      // mfma_f32_16x16x32_bf16: A m = lane&15, k = (lane>>4)*8 + j;
      // B n = lane&15 (Whr row); D col = lane&15, row = quad*4+reg.
      if (wg < 64) {
        const int m0  = (wg >> 4) * 16;
        const int n0  = (wg & 15) * 16;
        const int l16 = lane & 15;
        const int kh2 = (lane >> 4) * 8 + wave * 512;
        const unsigned* ahp = hP + (size_t)(m0 + l16) * H_ + kh2;   // sc1
        const float*    bwf = Whr + (size_t)(n0 + l16) * H_ + kh2;  // cached
        f32x4 phh = {}, phl = {}, plh = {};
#pragma unroll 8
        for (int k0 = 0; k0 < 512; k0 += 32) {
          short8 Ah, Al, Bh, Bl;
          unpack_a8(ahp + k0, Ah, Al);
          split8(bwf + k0, Bh, Bl);
          phh = __builtin_amdgcn_mfma_f32_16x16x32_bf16(Ah, Bh, phh, 0, 0, 0);
          phl = __builtin_amdgcn_mfma_f32_16x16x32_bf16(Ah, Bl, phl, 0, 0, 0);
          plh = __builtin_amdgcn_mfma_f32_16x16x32_bf16(Al, Bh, plh, 0, 0, 0);
        }
        f32x4 a4;
#pragma unroll
        for (int r = 0; r < 4; ++r) a4[r] = phh[r] + phl[r] + plh[r];
        if (wave == 1) *(f32x4*)&sRed[lane * 4] = a4;
        __syncthreads();
        if (wave == 0) {
          f32x4 o = *(const f32x4*)&sRed[lane * 4];
#pragma unroll
          for (int r = 0; r < 4; ++r) {
            int mm  = m0 + (lane >> 4) * 4 + r;
            int col = n0 + l16;
            float v = a4[r] + o[r];
            __hip_atomic_store(&yOut[((size_t)t * B_ + mm) * P_ + col], packf(v),
                               __ATOMIC_RELAXED, __HIP_MEMORY_SCOPE_AGENT);
            if (l == 3 && t == T_ - 1) out[mm * P_ + col] = v;
          }
        }
      }
      ep++; gbar(cnt, ep);
    }
  }
}

extern "C" void kernel_launch(void* const* d_in, const int* in_sizes, int n_in,
                              void* d_out, int out_size, void* d_ws, size_t ws_size,
                              hipStream_t stream) {
  const float* x    = (const float*)d_in[0];
  const float* Wih0 = (const float*)d_in[1];
  const float* Whh0 = (const float*)d_in[2];
  const float* bih0 = (const float*)d_in[3];
  const float* bhh0 = (const float*)d_in[4];
  const float* Whr0 = (const float*)d_in[5];
  const float* Wihs = (const float*)d_in[6];
  const float* Whhs = (const float*)d_in[7];
  const float* bihs = (const float*)d_in[8];
  const float* bhhs = (const float*)d_in[9];
  const float* Whrs = (const float*)d_in[10];
  float* out = (float*)d_out;

  char* ws = (char*)d_ws;
  unsigned* cnt = (unsigned*)ws;                       // 4 KB (stripes + release)
  unsigned* hP  = (unsigned*)(ws + 4096);              // 256 KB (B*H u32)
  unsigned* Y0  = (unsigned*)(ws + 4096 + 262144);     // 16 MB (T*B*P u32)
  // ping-pong second buffer if workspace allows, else in-place fallback
  const size_t need_pp = 4096 + 262144 + 2u * 16777216;
  unsigned* Y1 = (ws_size >= need_pp) ? (unsigned*)(ws + 4096 + 262144 + 16777216)
                                      : Y0;

  (void)hipMemsetAsync(d_ws, 0, 4096, stream);   // zero barrier counters

  void* args[] = {&x, &Wih0, &Whh0, &bih0, &bhh0, &Whr0,
                  &Wihs, &Whhs, &bihs, &bhhs, &Whrs,
                  &out, &Y0, &Y1, &hP, &cnt};
  (void)hipLaunchCooperativeKernel((void*)lstm_kernel, dim3(NWG), dim3(NTHR),
                                   args, 0, stream);
}